// Round 1
// 1566.449 us; speedup vs baseline: 1.8928x; 1.8928x over previous
//
#include <hip/hip_runtime.h>
#include <stdint.h>

typedef __attribute__((ext_vector_type(8))) short bf16x8;  // 8 bf16 in 4 VGPRs
typedef __attribute__((ext_vector_type(4))) float f32x4;

// f32 -> bf16 round-to-nearest-even (values are normal; no NaN handling needed)
__device__ __forceinline__ ushort f2bf(float f) {
    uint32_t u = __float_as_uint(f);
    return (ushort)((u + 0x7FFFu + ((u >> 16) & 1u)) >> 16);
}

// ---------------- level metadata (from torch-ngp GridEncoder __init__) -------
__device__ const int d_level_off[16] = {
    0, 4920, 40864, 315496, 839784, 1364072, 1888360, 2412648,
    2936936, 3461224, 3985512, 4509800, 5034088, 5558376, 6082664, 6606952
};

// ---------------- grid encode + affordance embedding -> bf16 comb ------------
// one thread per (point, level); writes comb[n, l*8 .. l*8+7] as bf16.
// rows [npts, npts_pad) are zero-filled so the MFMA GEMM needs no row guards.
__global__ __launch_bounds__(256) void grid_encode_kernel(
    const float* __restrict__ x, const float* __restrict__ aff,
    const float* __restrict__ table, const float* __restrict__ Wa,
    const float* __restrict__ ba, ushort* __restrict__ comb,
    int npts, int npts_pad)
{
    int t = blockIdx.x * 256 + threadIdx.x;
    int n = t >> 4;
    if (n >= npts_pad) return;
    int l = t & 15;
    int fb = l * 8;
    uint32_t pk[4] = {0u, 0u, 0u, 0u};

    if (n < npts) {
        float scale = (float)((16 << l) - 1);
        float fr[3];
        uint32_t cc[3];
        #pragma unroll
        for (int d = 0; d < 3; ++d) {
            float b   = (x[n * 3 + d] + 10.0f) / 20.0f;   // [-10,10] -> [0,1]
            float x01 = (b + 1.0f) * 0.5f;                // -> [0.5,1]
            float pos = x01 * scale + 0.5f;
            float pg  = floorf(pos);
            fr[d] = pos - pg;
            cc[d] = (uint32_t)(int)pg;
        }

        const bool dense = (l < 3);
        const uint32_t s1 = (uint32_t)(16 << l) + 1u;
        const uint32_t s2 = s1 * s1;
        const int off = d_level_off[l];

        float fa[8] = {0.f, 0.f, 0.f, 0.f, 0.f, 0.f, 0.f, 0.f};
        #pragma unroll
        for (int c = 0; c < 8; ++c) {
            uint32_t cx = cc[0] + (uint32_t)(c & 1);
            uint32_t cy = cc[1] + (uint32_t)((c >> 1) & 1);
            uint32_t cz = cc[2] + (uint32_t)((c >> 2) & 1);
            float w = ((c & 1) ? fr[0] : 1.0f - fr[0])
                    * ((c & 2) ? fr[1] : 1.0f - fr[1])
                    * ((c & 4) ? fr[2] : 1.0f - fr[2]);
            uint32_t idx;
            if (dense) idx = cx + cy * s1 + cz * s2;
            else       idx = (cx ^ (cy * 2654435761u) ^ (cz * 805459861u)) & 0x7FFFFu;
            const float4* p = (const float4*)(table + (size_t)(idx + (uint32_t)off) * 8u);
            float4 t0 = p[0];
            float4 t1 = p[1];
            fa[0] = fmaf(w, t0.x, fa[0]);
            fa[1] = fmaf(w, t0.y, fa[1]);
            fa[2] = fmaf(w, t0.z, fa[2]);
            fa[3] = fmaf(w, t0.w, fa[3]);
            fa[4] = fmaf(w, t1.x, fa[4]);
            fa[5] = fmaf(w, t1.y, fa[5]);
            fa[6] = fmaf(w, t1.z, fa[6]);
            fa[7] = fmaf(w, t1.w, fa[7]);
        }

        float av = aff[n];
        #pragma unroll
        for (int j = 0; j < 4; ++j) {
            float o0 = fa[2 * j]     + av * Wa[fb + 2 * j]     + ba[fb + 2 * j];
            float o1 = fa[2 * j + 1] + av * Wa[fb + 2 * j + 1] + ba[fb + 2 * j + 1];
            pk[j] = (uint32_t)f2bf(o0) | ((uint32_t)f2bf(o1) << 16);
        }
    }
    *(uint4*)(comb + (size_t)n * 128 + fb) = make_uint4(pk[0], pk[1], pk[2], pk[3]);
}

// ---------------- tiny precompute GEMMs (weight folding) ---------------------
__global__ void small_mm(const float* __restrict__ A, const float* __restrict__ B,
                         float* __restrict__ C, int Mo, int No, int Ko)
{
    int gid = blockIdx.x * 256 + threadIdx.x;
    if (gid >= Mo * No) return;
    int j = gid / No, k = gid % No;
    float s = 0.f;
    for (int i = 0; i < Ko; ++i) s = fmaf(A[j * Ko + i], B[i * No + k], s);
    C[gid] = s;
}

__global__ void small_mv(const float* __restrict__ A, const float* __restrict__ v,
                         const float* __restrict__ b0, float* __restrict__ out,
                         int Mo, int Ko)
{
    int j = blockIdx.x * 256 + threadIdx.x;
    if (j >= Mo) return;
    float s = b0[j];
    for (int i = 0; i < Ko; ++i) s = fmaf(A[j * Ko + i], v[i], s);
    out[j] = s;
}

__global__ void f32_to_bf16_kernel(const float* __restrict__ in,
                                   ushort* __restrict__ out, int n)
{
    int i = blockIdx.x * 256 + threadIdx.x;
    if (i < n) out[i] = f2bf(in[i]);
}

// ---------------- bf16 MFMA GEMM: C = A @ W^T (+bias) ------------------------
// A: [Mpad, K] bf16 row-major (M padded to 128, no row guards on loads)
// B: [N, K]    bf16 row-major (weights; N multiple of 128, K multiple of 64)
// mode 1: relu -> bf16 store to [Mpad, N]
// mode 2: fp32 split store: cols<512 -> out[r*512+c], cols>=512 -> +npts*512
// Structure: 128x128 tile, BK=64, 4 waves (2x2), wave = 64x64 via 4x4 x
// mfma_f32_16x16x32_bf16. Staging: global_load_lds width-16, linear LDS dest,
// inverse-XOR-swizzled global source; ds_read side applies byte^=((row&7)<<4)
// so the 128B-row-stride ds_read_b128 is bank-conflict-free (G4).
__global__ __launch_bounds__(256) void gemm_mfma(
    const ushort* __restrict__ A, const ushort* __restrict__ B,
    const float* __restrict__ bias, void* __restrict__ Cv,
    int N, int K, int mode, int npts)
{
    __shared__ ushort As[128 * 64];
    __shared__ ushort Bs[128 * 64];

    const int tid  = threadIdx.x;
    const int bn   = blockIdx.x;
    const int bm   = blockIdx.y;
    const int lane = tid & 63;
    const int wave = tid >> 6;
    const int wm   = wave >> 1, wn = wave & 1;     // 2x2 wave grid
    const int l15  = lane & 15, lhi = lane >> 4;   // frag row / k-group

    f32x4 acc[4][4] = {};

    // staging chunk map: chunk c holds global k-group ((c&7)^(row&7)) of row c>>3
    int rowc[4], kcc[4];
    #pragma unroll
    for (int i = 0; i < 4; ++i) {
        int c = tid + i * 256;
        rowc[i] = c >> 3;
        kcc[i]  = ((c & 7) ^ (rowc[i] & 7)) * 8;   // bf16 elems within BK
    }

    for (int k0 = 0; k0 < K; k0 += 64) {
        #pragma unroll
        for (int i = 0; i < 4; ++i) {
            int c = tid + i * 256;
            const ushort* ga = A + (size_t)(bm * 128 + rowc[i]) * (size_t)K + (k0 + kcc[i]);
            __builtin_amdgcn_global_load_lds(
                (const __attribute__((address_space(1))) uint32_t*)ga,
                (__attribute__((address_space(3))) uint32_t*)&As[c * 8], 16, 0, 0);
            const ushort* gb = B + (size_t)(bn * 128 + rowc[i]) * (size_t)K + (k0 + kcc[i]);
            __builtin_amdgcn_global_load_lds(
                (const __attribute__((address_space(1))) uint32_t*)gb,
                (__attribute__((address_space(3))) uint32_t*)&Bs[c * 8], 16, 0, 0);
        }
        __syncthreads();   // compiler drains vmcnt(0) before s_barrier

        #pragma unroll
        for (int kk = 0; kk < 64; kk += 32) {
            bf16x8 a[4], b[4];
            int ks = (kk >> 3) + lhi;              // 16B-slot index within row
            #pragma unroll
            for (int f = 0; f < 4; ++f) {
                int ra = wm * 64 + f * 16 + l15;
                a[f] = *(const bf16x8*)&As[ra * 64 + ((ks ^ (ra & 7)) << 3)];
                int rb = wn * 64 + f * 16 + l15;
                b[f] = *(const bf16x8*)&Bs[rb * 64 + ((ks ^ (rb & 7)) << 3)];
            }
            #pragma unroll
            for (int i = 0; i < 4; ++i)
                #pragma unroll
                for (int j = 0; j < 4; ++j)
                    acc[i][j] = __builtin_amdgcn_mfma_f32_16x16x32_bf16(
                        a[i], b[j], acc[i][j], 0, 0, 0);
        }
        __syncthreads();   // protect LDS before next stage
    }

    // epilogue. C/D layout: col = lane&15 (n), row = (lane>>4)*4 + reg (m).
    float bb[4];
    #pragma unroll
    for (int j = 0; j < 4; ++j)
        bb[j] = bias[bn * 128 + wn * 64 + j * 16 + l15];

    if (mode == 1) {
        ushort* Cb = (ushort*)Cv;
        #pragma unroll
        for (int i = 0; i < 4; ++i) {
            #pragma unroll
            for (int r = 0; r < 4; ++r) {
                int m = bm * 128 + wm * 64 + i * 16 + lhi * 4 + r;
                ushort* dst = Cb + (size_t)m * N + bn * 128 + wn * 64 + l15;
                #pragma unroll
                for (int j = 0; j < 4; ++j) {
                    float v = acc[i][j][r] + bb[j];
                    dst[j * 16] = f2bf(fmaxf(v, 0.f));
                }
            }
        }
    } else {
        float* out = (float*)Cv;
        const int nh = (bn >= 4);
        float* plane = out + (nh ? (size_t)npts * 512 : 0);
        const int ncol = bn * 128 - nh * 512 + wn * 64 + l15;
        #pragma unroll
        for (int i = 0; i < 4; ++i) {
            #pragma unroll
            for (int r = 0; r < 4; ++r) {
                int m = bm * 128 + wm * 64 + i * 16 + lhi * 4 + r;
                if (m < npts) {
                    float* dst = plane + (size_t)m * 512 + ncol;
                    #pragma unroll
                    for (int j = 0; j < 4; ++j)
                        dst[j * 16] = acc[i][j][r] + bb[j];
                }
            }
        }
    }
}

// ---------------- launch ------------------------------------------------------
extern "C" void kernel_launch(void* const* d_in, const int* in_sizes, int n_in,
                              void* d_out, int out_size, void* d_ws, size_t ws_size,
                              hipStream_t stream)
{
    const float* x     = (const float*)d_in[0];
    const float* aff   = (const float*)d_in[1];
    const float* table = (const float*)d_in[2];
    const float* Wa    = (const float*)d_in[3];
    const float* ba    = (const float*)d_in[4];
    // d_in[5..8] = Wq,bq,Wk,bk — unused (softmax over a single key == 1)
    const float* Wv    = (const float*)d_in[9];
    const float* bv    = (const float*)d_in[10];
    const float* Wo    = (const float*)d_in[11];
    const float* bo    = (const float*)d_in[12];
    const float* W1    = (const float*)d_in[13];
    const float* b1    = (const float*)d_in[14];
    const float* W2    = (const float*)d_in[15];
    const float* b2    = (const float*)d_in[16];
    const float* W3    = (const float*)d_in[17];
    const float* b3    = (const float*)d_in[18];
    const int npts = in_sizes[0] / 3;
    const int mb = (npts + 127) / 128;
    const int npts_pad = mb * 128;

    float* ws = (float*)d_ws;
    float*  Wvo  = ws;                          // 16384 f32
    float*  bvo  = ws + 16384;                  // 128
    float*  W1c  = ws + 16512;                  // 256*128 f32
    float*  b1c  = ws + 49280;                  // 256
    ushort* W1cb = (ushort*)(ws + 49536);       // 32768 bf16  (16384 f32 slots)
    ushort* W2b  = (ushort*)(ws + 65920);       // 65536 bf16  (32768 slots)
    ushort* W3b  = (ushort*)(ws + 98688);       // 262144 bf16 (131072 slots)
    ushort* comb = (ushort*)(ws + 229760);      // [npts_pad,128] bf16
    ushort* h1   = comb + (size_t)npts_pad * 128;   // [npts_pad,256] bf16
    ushort* h2   = h1   + (size_t)npts_pad * 256;   // [npts_pad,256] bf16

    // fold v/attn chain into W1: h1 = relu(comb @ (W1·Wo·Wv)^T + (W1·(Wo·bv+bo)+b1))
    small_mm<<<64, 256, 0, stream>>>(Wo, Wv, Wvo, 128, 128, 128);
    small_mv<<<1, 256, 0, stream>>>(Wo, bv, bo, bvo, 128, 128);
    small_mm<<<128, 256, 0, stream>>>(W1, Wvo, W1c, 256, 128, 128);
    small_mv<<<1, 256, 0, stream>>>(W1, bvo, b1, b1c, 256, 128);

    // bf16 weight planes
    f32_to_bf16_kernel<<<128, 256, 0, stream>>>(W1c, W1cb, 32768);
    f32_to_bf16_kernel<<<256, 256, 0, stream>>>(W2, W2b, 65536);
    f32_to_bf16_kernel<<<1024, 256, 0, stream>>>(W3, W3b, 262144);

    grid_encode_kernel<<<(npts_pad * 16) / 256, 256, 0, stream>>>(
        x, aff, table, Wa, ba, comb, npts, npts_pad);

    // h1 = relu(comb @ W1c^T + b1c)         [K=128, N=256]
    gemm_mfma<<<dim3(2, mb), 256, 0, stream>>>(comb, W1cb, b1c, h1, 256, 128, 1, npts);
    // h2 = relu(h1 @ W2^T + b2)             [K=256, N=256]
    gemm_mfma<<<dim3(2, mb), 256, 0, stream>>>(h1, W2b, b2, h2, 256, 256, 1, npts);
    // out = h2 @ W3^T + b3, split-stored    [K=256, N=1024]
    gemm_mfma<<<dim3(8, mb), 256, 0, stream>>>(h2, W3b, b3, d_out, 1024, 256, 2, npts);
}